// Round 4
// baseline (392.650 us; speedup 1.0000x reference)
//
#include <hip/hip_runtime.h>
#include <hip/hip_bf16.h>
#include <math.h>

// Problem constants
#define BB    2
#define NN    1024
#define PAST  1024
#define KVL   2048            // PAST + NN
#define DIM   2048
#define HEADS 16
#define DH    128
#define INNER 2048            // HEADS*DH
#define NQKV  6144            // 3*INNER
#define TOK   2048            // BB*NN
#define LN_EPS 1e-5f

typedef __attribute__((ext_vector_type(8)))  short    short8;   // 8 bf16
typedef __attribute__((ext_vector_type(4)))  float    f32x4;
typedef __attribute__((ext_vector_type(16))) float    f32x16;
typedef __attribute__((ext_vector_type(8)))  unsigned short us8;
typedef __attribute__((ext_vector_type(4)))  unsigned short us4;
typedef unsigned short us;

__device__ __forceinline__ float bfbits2f(us u) {
    return __uint_as_float(((unsigned int)u) << 16);
}
__device__ __forceinline__ us f2bfb(float f) {
    union { __hip_bfloat16 h; us u; } cv;
    cv.h = __float2bfloat16(f);           // RNE
    return cv.u;
}
__device__ __forceinline__ unsigned pkbf(float a, float b) {
    return (unsigned)f2bfb(a) | ((unsigned)f2bfb(b) << 16);
}
__device__ __forceinline__ us8 pack8u(float4 a, float4 b) {
    us8 r;
    r[0] = f2bfb(a.x); r[1] = f2bfb(a.y); r[2] = f2bfb(a.z); r[3] = f2bfb(a.w);
    r[4] = f2bfb(b.x); r[5] = f2bfb(b.y); r[6] = f2bfb(b.z); r[7] = f2bfb(b.w);
    return r;
}

// async global->LDS, 16B per lane. LDS dest must be linear (base + lane*16);
// swizzled layouts are achieved by pre-swizzling the GLOBAL source address.
__device__ __forceinline__ void gload_lds16(const void* gsrc, void* ldst) {
    __builtin_amdgcn_global_load_lds(
        (const __attribute__((address_space(1))) void*)gsrc,
        (__attribute__((address_space(3))) void*)ldst, 16, 0, 0);
}

// ---------------------------------------------------------------------------
// K0: transpose + cast: dst[C][R] (bf16) <- src[R][C] (f32). 64x64 tiles.
// ---------------------------------------------------------------------------
__global__ __launch_bounds__(256) void transp_kernel(
    const float* __restrict__ src, us* __restrict__ dst, int R, int C)
{
    const int c0 = blockIdx.x * 64;
    const int r0 = blockIdx.y * 64;
    const int tid = threadIdx.x;

    __shared__ us T[64][68];

    #pragma unroll
    for (int e = 0; e < 4; e++) {
        int idx = tid + e * 256;
        int jr  = idx >> 4;               // row within tile
        int c4  = (idx & 15) * 4;
        float4 v = *reinterpret_cast<const float4*>(
            src + (size_t)(r0 + jr) * C + c0 + c4);
        us4 w;
        w[0] = f2bfb(v.x); w[1] = f2bfb(v.y); w[2] = f2bfb(v.z); w[3] = f2bfb(v.w);
        *reinterpret_cast<us4*>(&T[jr][c4]) = w;
    }
    __syncthreads();

    #pragma unroll
    for (int e = 0; e < 4; e++) {
        int idx = tid + e * 256;
        int d   = idx >> 4;               // col within tile (dst row)
        int k4  = (idx & 15) * 4;
        us4 w;
        w[0] = T[k4 + 0][d];
        w[1] = T[k4 + 1][d];
        w[2] = T[k4 + 2][d];
        w[3] = T[k4 + 3][d];
        *reinterpret_cast<us4*>(dst + (size_t)(c0 + d) * R + r0 + k4) = w;
    }
}

// ---------------------------------------------------------------------------
// K1: LayerNorm over DIM=2048 -> bf16. One block per token.
// ---------------------------------------------------------------------------
__global__ __launch_bounds__(256) void ln_kernel(
    const float* __restrict__ x, const float* __restrict__ g,
    const float* __restrict__ b, us* __restrict__ xn)
{
    const int t   = blockIdx.x;
    const int tid = threadIdx.x;
    const size_t base = (size_t)t * DIM;

    float4 p0 = reinterpret_cast<const float4*>(x + base)[tid * 2 + 0];
    float4 p1 = reinterpret_cast<const float4*>(x + base)[tid * 2 + 1];
    float v[8] = {p0.x, p0.y, p0.z, p0.w, p1.x, p1.y, p1.z, p1.w};

    float s1 = 0.f, s2 = 0.f;
    #pragma unroll
    for (int i = 0; i < 8; i++) { s1 += v[i]; s2 += v[i] * v[i]; }

    #pragma unroll
    for (int off = 32; off; off >>= 1) {
        s1 += __shfl_xor(s1, off);
        s2 += __shfl_xor(s2, off);
    }
    __shared__ float red1[4], red2[4];
    if ((tid & 63) == 0) { red1[tid >> 6] = s1; red2[tid >> 6] = s2; }
    __syncthreads();
    float S1 = red1[0] + red1[1] + red1[2] + red1[3];
    float S2 = red2[0] + red2[1] + red2[2] + red2[3];
    const float inv = 1.0f / (float)DIM;
    float mu  = S1 * inv;
    float var = S2 * inv - mu * mu;
    float rstd = rsqrtf(var + LN_EPS);

    const int d0 = tid * 8;
    float4 oa, ob;
    oa.x = (v[0] - mu) * rstd * g[d0 + 0] + b[d0 + 0];
    oa.y = (v[1] - mu) * rstd * g[d0 + 1] + b[d0 + 1];
    oa.z = (v[2] - mu) * rstd * g[d0 + 2] + b[d0 + 2];
    oa.w = (v[3] - mu) * rstd * g[d0 + 3] + b[d0 + 3];
    ob.x = (v[4] - mu) * rstd * g[d0 + 4] + b[d0 + 4];
    ob.y = (v[5] - mu) * rstd * g[d0 + 5] + b[d0 + 5];
    ob.z = (v[6] - mu) * rstd * g[d0 + 6] + b[d0 + 6];
    ob.w = (v[7] - mu) * rstd * g[d0 + 7] + b[d0 + 7];

    *reinterpret_cast<us8*>(xn + base + d0) = pack8u(oa, ob);
}

// ---------------------------------------------------------------------------
// K2/K5: MFMA GEMM (B^T layout):  C[M][N] = A[M][K] @ Bt[N][K]^T  (bf16 in)
// 128x128 tile, BK=32, 3-buffer LDS ring + counted vmcnt (stage k+2 in
// flight across the barrier). LDS geometry: 64 rows x 128 B (two m-rows per
// LDS row), XOR-swizzled ^((row&7)<<4) via pre-swizzled gload source ->
// fragment ds_read_b128 hits 32 banks at 2 lanes/bank (conflict-free).
// ---------------------------------------------------------------------------
template<bool OUT_BF16>
__global__ __launch_bounds__(256) void gemm_bt_kernel(
    const us* __restrict__ A, const us* __restrict__ Bt,
    void* __restrict__ Cout, int M, int N, int K)
{
    __shared__ us As[3][128 * 32];     // 8 KB per buffer
    __shared__ us Bs[3][128 * 32];

    const int tid  = threadIdx.x;
    const int wave = tid >> 6, lane = tid & 63;
    const int quad = lane >> 4, l16 = lane & 15;
    const int wm = wave & 1, wn = wave >> 1;
    const int m0 = blockIdx.y * 128, n0 = blockIdx.x * 128;

    f32x4 acc[4][4];
    #pragma unroll
    for (int i = 0; i < 4; i++)
        #pragma unroll
        for (int j = 0; j < 4; j++)
            #pragma unroll
            for (int r = 0; r < 4; r++) acc[i][j][r] = 0.f;

    auto stage = [&](int k0, int buf) {
        #pragma unroll
        for (int e = 0; e < 2; e++) {
            int phys = (e * 256 + tid) * 16;
            int lr   = phys >> 7;                        // LDS row (128 B)
            int offp = (phys & 127) ^ ((lr & 7) << 4);   // logical offset
            int m    = 2 * lr + (offp >> 6);             // m-row in pair
            int kb   = offp & 63;                        // byte within BK=32
            gload_lds16((const char*)(A + (size_t)(m0 + m) * K + k0) + kb,
                        (char*)&As[buf][0] + phys);
            gload_lds16((const char*)(Bt + (size_t)(n0 + m) * K + k0) + kb,
                        (char*)&Bs[buf][0] + phys);
        }
    };

    const int ns = K >> 5;
    stage(0, 0);
    stage(32, 1);
    __builtin_amdgcn_sched_barrier(0);
    asm volatile("s_waitcnt vmcnt(4)" ::: "memory");
    __builtin_amdgcn_s_barrier();
    __builtin_amdgcn_sched_barrier(0);

    int cur = 0;
    for (int ks = 0; ks < ns; ks++) {
        if (ks + 2 < ns) stage((ks + 2) * 32, (ks + 2) % 3);

        short8 af[4], bf[4];
        #pragma unroll
        for (int mi = 0; mi < 4; mi++) {
            int mrow = wm * 64 + mi * 16 + l16;
            int lr   = mrow >> 1;
            int off  = ((mrow & 1) * 64 + quad * 16) ^ ((lr & 7) << 4);
            af[mi] = *reinterpret_cast<const short8*>(
                (const char*)&As[cur][0] + lr * 128 + off);
        }
        #pragma unroll
        for (int ni = 0; ni < 4; ni++) {
            int nrow = wn * 64 + ni * 16 + l16;
            int lr   = nrow >> 1;
            int off  = ((nrow & 1) * 64 + quad * 16) ^ ((lr & 7) << 4);
            bf[ni] = *reinterpret_cast<const short8*>(
                (const char*)&Bs[cur][0] + lr * 128 + off);
        }

        __builtin_amdgcn_s_setprio(1);
        #pragma unroll
        for (int mi = 0; mi < 4; mi++)
            #pragma unroll
            for (int ni = 0; ni < 4; ni++)
                acc[mi][ni] = __builtin_amdgcn_mfma_f32_16x16x32_bf16(
                    af[mi], bf[ni], acc[mi][ni], 0, 0, 0);
        __builtin_amdgcn_s_setprio(0);

        __builtin_amdgcn_sched_barrier(0);
        if (ks + 2 < ns) asm volatile("s_waitcnt vmcnt(4)" ::: "memory");
        else             asm volatile("s_waitcnt vmcnt(0)" ::: "memory");
        __builtin_amdgcn_s_barrier();
        __builtin_amdgcn_sched_barrier(0);
        cur = (cur == 2) ? 0 : cur + 1;
    }

    // epilogue: C/D layout col=l16, row=quad*4+r
    #pragma unroll
    for (int mi = 0; mi < 4; mi++) {
        #pragma unroll
        for (int r = 0; r < 4; r++) {
            size_t row = (size_t)(m0 + wm * 64 + mi * 16 + quad * 4 + r);
            #pragma unroll
            for (int ni = 0; ni < 4; ni++) {
                size_t col = n0 + wn * 64 + ni * 16 + l16;
                if (OUT_BF16)
                    ((us*)Cout)[row * N + col] = f2bfb(acc[mi][ni][r]);
                else
                    ((float*)Cout)[row * N + col] = acc[mi][ni][r];
            }
        }
    }
}

// ---------------------------------------------------------------------------
// K3: RoPE + KV cache assembly. qkv is bf16; outputs f32 + bf16 K copy.
// ---------------------------------------------------------------------------
__global__ __launch_bounds__(256) void rope_kernel(
    const float* __restrict__ past_k, const float* __restrict__ past_v,
    us* __restrict__ qkv, float* __restrict__ out_k, float* __restrict__ out_v,
    us* __restrict__ Kbf)
{
    const int tid  = threadIdx.x;
    const int pid  = blockIdx.x * 4 + (tid >> 6);
    const int lane = tid & 63;

    const int b   = pid / (HEADS * KVL);
    const int rem = pid - b * (HEADS * KVL);
    const int h   = rem / KVL;
    const int pos = rem - h * KVL;

    const float invf = exp2f((float)lane * (-13.287712379549449f / 64.0f));
    float sn, cs;
    sincosf((float)pos * invf, &sn, &cs);

    const size_t obase = ((size_t)(b * HEADS + h) * KVL + pos) * DH + 2 * lane;

    float k0, k1;
    if (pos < PAST) {
        const size_t pbase = ((size_t)(b * HEADS + h) * PAST + pos) * DH + 2 * lane;
        k0 = past_k[pbase];
        k1 = past_k[pbase + 1];
    } else {
        const int t = b * NN + (pos - PAST);
        const us* qp = qkv + (size_t)t * NQKV + INNER + h * DH + 2 * lane;
        k0 = bfbits2f(qp[0]); k1 = bfbits2f(qp[1]);
    }
    float kr0 = k0 * cs - k1 * sn;
    float kr1 = k1 * cs + k0 * sn;
    out_k[obase]     = kr0;
    out_k[obase + 1] = kr1;
    Kbf[obase]       = f2bfb(kr0);
    Kbf[obase + 1]   = f2bfb(kr1);

    if (pos < PAST) {
        const size_t pbase = ((size_t)(b * HEADS + h) * PAST + pos) * DH + 2 * lane;
        out_v[obase]     = past_v[pbase];
        out_v[obase + 1] = past_v[pbase + 1];
    } else {
        const int t = b * NN + (pos - PAST);
        const us* vp = qkv + (size_t)t * NQKV + 2 * INNER + h * DH + 2 * lane;
        out_v[obase]     = bfbits2f(vp[0]);
        out_v[obase + 1] = bfbits2f(vp[1]);
    }

    if (pos >= PAST) {
        const int t = b * NN + (pos - PAST);
        us* qq = qkv + (size_t)t * NQKV + h * DH + 2 * lane;
        float q0 = bfbits2f(qq[0]), q1 = bfbits2f(qq[1]);
        qq[0] = f2bfb(q0 * cs - q1 * sn);
        qq[1] = f2bfb(q1 * cs + q0 * sn);
    }
}

// ---------------------------------------------------------------------------
// K3b: V transpose to bf16: Vtg[bh][d][kv] <- bf16(out_v[bh][kv][d])
// ---------------------------------------------------------------------------
__global__ __launch_bounds__(256) void vtrans_kernel(
    const float* __restrict__ Vc, us* __restrict__ Vtg)
{
    const int jb = blockIdx.x;
    const int db = blockIdx.y;
    const int bh = blockIdx.z;
    const int tid = threadIdx.x;

    __shared__ us T[64][68];

    const float* src = Vc + ((size_t)bh * KVL + jb * 64) * DH + db * 64;
    #pragma unroll
    for (int e = 0; e < 4; e++) {
        int idx = tid + e * 256;
        int jr  = idx >> 4;
        int c4  = (idx & 15) * 4;
        float4 v = *reinterpret_cast<const float4*>(src + (size_t)jr * DH + c4);
        us4 w;
        w[0] = f2bfb(v.x); w[1] = f2bfb(v.y); w[2] = f2bfb(v.z); w[3] = f2bfb(v.w);
        *reinterpret_cast<us4*>(&T[jr][c4]) = w;
    }
    __syncthreads();

    us* dst = Vtg + ((size_t)bh * DH + db * 64) * KVL + jb * 64;
    #pragma unroll
    for (int e = 0; e < 4; e++) {
        int idx = tid + e * 256;
        int d   = idx >> 4;
        int k4  = (idx & 15) * 4;
        us4 w;
        w[0] = T[k4 + 0][d];
        w[1] = T[k4 + 1][d];
        w[2] = T[k4 + 2][d];
        w[3] = T[k4 + 3][d];
        *reinterpret_cast<us4*>(dst + (size_t)d * KVL + k4) = w;
    }
}

// ---------------------------------------------------------------------------
// K4: MFMA flash attention — 32x32x16 MFMA, 32 q-rows/wave, 4 waves/block.
// Swapped QK^T: S col=q=lane&31, row=kv=(reg&3)+8*(reg>>2)+4*(lane>>5).
// PV A-fragment built fully in-register via cvt_pk + v_permlane32_swap_b32
// (no P LDS buffer). K/V staged through a 3-buffer LDS ring with counted
// vmcnt so stage loads stay in flight across barriers. Paired q-tiles
// {p, 15-p} per block (uniform 49 wave-chunks); XCD-local (b,h) grouping.
// ---------------------------------------------------------------------------
__global__ __launch_bounds__(256) void attn_mfma_kernel(
    const us* __restrict__ qkv,               // [TOK][NQKV] bf16, q roped
    const us* __restrict__ Kbf,               // [bh][KVL][DH] bf16 (roped)
    const us* __restrict__ Vtg,               // [bh][DH][KVL] bf16
    us* __restrict__ Ao)                      // [TOK][INNER] bf16
{
    const int tid  = threadIdx.x;
    const int wave = tid >> 6;
    const int lane = tid & 63;
    const int l32  = lane & 31;
    const int g    = lane >> 5;

    // XCD-aware decode: blk%8 -> XCD; each XCD owns 4 (b,h) groups.
    const int flat = blockIdx.x;
    const int s    = flat >> 3;                 // 0..31
    const int grp  = (flat & 7) + 8 * (s & 3);  // group = h + 16*b
    const int p    = s >> 2;                    // pair 0..7
    const int h    = grp & 15;
    const int b    = grp >> 4;
    const int qtile = (wave < 2) ? p : (15 - p);
    const int qsub  = (wave & 1) * 32;
    const int mynch = 17 + qtile;
    const int nch   = 32 - p;

    __shared__ us Ks[3][64 * 128];   // 16 KB x3, swizzled rows of 256 B
    __shared__ us Vt[3][128 * 64];   // 16 KB x3, swizzled rows of 128 B

    // Q B-fragments: col=q=lane&31, k = ks*16 + 8*(lane>>5) + e
    short8 qf[8];
    {
        const int qrow = qtile * 64 + qsub + l32;
        const us* qp = qkv + (size_t)(b * NN + qrow) * NQKV + h * DH;
        #pragma unroll
        for (int ks = 0; ks < 8; ks++)
            qf[ks] = *reinterpret_cast<const short8*>(qp + ks * 16 + g * 8);
    }

    f32x16 Oacc[4];
    #pragma unroll
    for (int dt = 0; dt < 4; dt++)
        #pragma unroll
        for (int r = 0; r < 16; r++) Oacc[dt][r] = 0.f;
    float m_run  = -INFINITY;       // running max for q-col (unscaled)
    float l_part = 0.f;             // partial denom over this half's kv

    const us* kptr = Kbf + (size_t)(b * HEADS + h) * KVL * DH;
    const us* vtb  = Vtg + (size_t)(b * HEADS + h) * DH * KVL;
    const float scale = 0.08838834764831845f;
    const float THRU  = 90.50966799f;          // 8 / scale
    const int qg = PAST + qtile * 64 + qsub + l32;

    auto stage = [&](int j0, int buf) {
        // K chunk: 64 rows x 256 B, XOR-swizzled via pre-swizzled global src
        #pragma unroll
        for (int e = 0; e < 4; e++) {
            int phys = (e * 256 + tid) * 16;
            int row  = phys >> 8;
            int col  = (phys & 255) ^ ((row & 7) << 4);
            gload_lds16((const char*)(kptr + (size_t)(j0 + row) * DH) + col,
                        (char*)&Ks[buf][0] + phys);
        }
        // V chunk: 128 rows x 128 B
        #pragma unroll
        for (int e = 0; e < 4; e++) {
            int phys = (e * 256 + tid) * 16;
            int row  = phys >> 7;
            int col  = (phys & 127) ^ ((row & 7) << 4);
            gload_lds16((const char*)(vtb + (size_t)row * KVL) + j0 * 2 + col,
                        (char*)&Vt[buf][0] + phys);
        }
    };

    stage(0, 0);
    stage(64, 1);
    __builtin_amdgcn_sched_barrier(0);
    asm volatile("s_waitcnt vmcnt(8)" ::: "memory");
    __builtin_amdgcn_s_barrier();
    __builtin_amdgcn_sched_barrier(0);

    int cur = 0;
    for (int c = 0; c < nch; c++) {
        const int j0 = c * 64;
        if (c + 2 < nch) stage(j0 + 128, (c + 2) % 3 == 0 ? 0 : ((c + 2) % 3));

        if (c < mynch) {
            // ---- QK^T: S[t] = K_tile(t) x Q ----
            f32x16 S[2];
            #pragma unroll
            for (int t = 0; t < 2; t++)
                #pragma unroll
                for (int r = 0; r < 16; r++) S[t][r] = 0.f;

            __builtin_amdgcn_s_setprio(1);
            #pragma unroll
            for (int ks = 0; ks < 8; ks++) {
                #pragma unroll
                for (int t = 0; t < 2; t++) {
                    int row  = t * 32 + l32;
                    int colb = ks * 32 + g * 16;
                    const char* kp = (const char*)&Ks[cur][0] +
                                     row * 256 + (colb ^ ((row & 7) << 4));
                    short8 kb = *reinterpret_cast<const short8*>(kp);
                    S[t] = __builtin_amdgcn_mfma_f32_32x32x16_bf16(
                        kb, qf[ks], S[t], 0, 0, 0);
                }
            }
            __builtin_amdgcn_s_setprio(0);

            // ---- mask + in-lane col max ----
            const int rel = qg - j0;
            float mx = -INFINITY;
            #pragma unroll
            for (int t = 0; t < 2; t++)
                #pragma unroll
                for (int r = 0; r < 16; r++) {
                    int kvo = t * 32 + (r & 3) + 8 * (r >> 2) + 4 * g;
                    S[t][r] = (kvo <= rel) ? S[t][r] : -INFINITY;
                    mx = fmaxf(mx, S[t][r]);
                }
            mx = fmaxf(mx, __shfl_xor(mx, 32));

            // ---- defer-max rescale (rare) ----
            float alpha = 1.f;
            if (__any(mx > m_run + THRU)) {
                float nm = fmaxf(m_run, mx);
                alpha = __expf((m_run - nm) * scale);
                m_run = nm;
                #pragma unroll
                for (int r = 0; r < 16; r++) {
                    float ar = __shfl(alpha, (r & 3) + 8 * (r >> 2) + 4 * g);
                    Oacc[0][r] *= ar; Oacc[1][r] *= ar;
                    Oacc[2][r] *= ar; Oacc[3][r] *= ar;
                }
            }

            // ---- P = exp(S*scale - m*scale), partial sum ----
            const float nmk = -m_run * scale;
            float rs = 0.f;
            #pragma unroll
            for (int t = 0; t < 2; t++)
                #pragma unroll
                for (int r = 0; r < 16; r++) {
                    float pv = __expf(fmaf(S[t][r], scale, nmk));
                    S[t][r] = pv;
                    rs += pv;
                }
            l_part = l_part * alpha + rs;

            // ---- build PV A-fragments in-register (cvt_pk + permlane) ----
            // frag(ks=2t+u) elem e=4a+i <- group-a lane's S[t][i + 4*(2u+g)]
            short8 paf[4];
            #pragma unroll
            for (int t = 0; t < 2; t++)
                #pragma unroll
                for (int u = 0; u < 2; u++) {
                    unsigned cA = pkbf(S[t][8*u + 0], S[t][8*u + 1]);
                    unsigned cB = pkbf(S[t][8*u + 2], S[t][8*u + 3]);
                    unsigned dA = pkbf(S[t][8*u + 4], S[t][8*u + 5]);
                    unsigned dB = pkbf(S[t][8*u + 6], S[t][8*u + 7]);
                    asm volatile("v_permlane32_swap_b32 %0, %1"
                                 : "+v"(cA), "+v"(dA));
                    asm volatile("v_permlane32_swap_b32 %0, %1"
                                 : "+v"(cB), "+v"(dB));
                    union { unsigned u4[4]; short8 s8; } fb;
                    fb.u4[0] = cA; fb.u4[1] = cB; fb.u4[2] = dA; fb.u4[3] = dB;
                    paf[t * 2 + u] = fb.s8;
                }

            // ---- PV ----
            __builtin_amdgcn_s_setprio(1);
            #pragma unroll
            for (int ks = 0; ks < 4; ks++) {
                #pragma unroll
                for (int dt = 0; dt < 4; dt++) {
                    int row  = dt * 32 + l32;
                    int colb = ks * 32 + g * 16;
                    const char* vp = (const char*)&Vt[cur][0] +
                                     row * 128 + (colb ^ ((row & 7) << 4));
                    short8 vb = *reinterpret_cast<const short8*>(vp);
                    Oacc[dt] = __builtin_amdgcn_mfma_f32_32x32x16_bf16(
                        paf[ks], vb, Oacc[dt], 0, 0, 0);
                }
            }
            __builtin_amdgcn_s_setprio(0);
        }

        __builtin_amdgcn_sched_barrier(0);
        if (c + 2 < nch) asm volatile("s_waitcnt vmcnt(8)" ::: "memory");
        else             asm volatile("s_waitcnt vmcnt(0)" ::: "memory");
        __builtin_amdgcn_s_barrier();
        __builtin_amdgcn_sched_barrier(0);
        cur = (cur == 2) ? 0 : cur + 1;
    }

    // final denom: combine g-halves (cols identical), per-row redistribute
    l_part += __shfl_xor(l_part, 32);
    float linv = 1.f / l_part;
    #pragma unroll
    for (int r = 0; r < 16; r++) {
        int qr = (r & 3) + 8 * (r >> 2) + 4 * g;
        float iv = __shfl(linv, qr);
        int qrow = qtile * 64 + qsub + qr;
        us* dst = Ao + (size_t)(b * NN + qrow) * INNER + h * DH + l32;
        #pragma unroll
        for (int dt = 0; dt < 4; dt++)
            dst[dt * 32] = f2bfb(Oacc[dt][r] * iv);
    }
}

// ---------------------------------------------------------------------------
extern "C" void kernel_launch(void* const* d_in, const int* in_sizes, int n_in,
                              void* d_out, int out_size, void* d_ws, size_t ws_size,
                              hipStream_t stream)
{
    const float* x      = (const float*)d_in[0];
    const float* past_k = (const float*)d_in[1];
    const float* past_v = (const float*)d_in[2];
    // d_in[3] = mask (unused; computed analytically)
    const float* w_qkv  = (const float*)d_in[4];
    const float* w_out  = (const float*)d_in[5];
    const float* ln_g   = (const float*)d_in[6];
    const float* ln_b   = (const float*)d_in[7];

    float* out   = (float*)d_out;                      // [B,N,DIM]
    float* out_k = out   + (size_t)BB * NN * DIM;      // [B,H,KVL,DH]
    float* out_v = out_k + (size_t)BB * HEADS * KVL * DH;

    // ws (bf16 buffers), 80 MB total:
    us* xn   = (us*)d_ws;                              // [TOK][DIM]     8 MB
    us* qkv  = xn  + (size_t)TOK * DIM;                // [TOK][NQKV]   24 MB
    us* Wqt  = qkv + (size_t)TOK * NQKV;               // [NQKV][DIM]   24 MB
    us* Wot  = Wqt + (size_t)NQKV * DIM;               // [DIM][INNER]   8 MB
    us* Vtg  = Wot + (size_t)DIM * INNER;              // [bh][DH][KVL] 16 MB
    us* attn = xn;   // alias: xn dead after qkv GEMM  // [TOK][INNER]   8 MB
    us* Kbf  = Wqt;  // alias: Wqt dead after qkv GEMM // [bh][KVL][DH] 16.7 MB

    transp_kernel<<<dim3(NQKV / 64, DIM / 64), 256, 0, stream>>>(
        w_qkv, Wqt, DIM, NQKV);
    transp_kernel<<<dim3(DIM / 64, INNER / 64), 256, 0, stream>>>(
        w_out, Wot, INNER, DIM);

    ln_kernel<<<TOK, 256, 0, stream>>>(x, ln_g, ln_b, xn);

    gemm_bt_kernel<true><<<dim3(NQKV / 128, TOK / 128), 256, 0, stream>>>(
        xn, Wqt, (void*)qkv, TOK, NQKV, DIM);

    rope_kernel<<<(BB * HEADS * KVL) / 4, 256, 0, stream>>>(
        past_k, past_v, qkv, out_k, out_v, Kbf);

    vtrans_kernel<<<dim3(KVL / 64, DH / 64, BB * HEADS), 256, 0, stream>>>(
        out_v, Vtg);

    attn_mfma_kernel<<<256, 256, 0, stream>>>(
        qkv, Kbf, Vtg, attn);

    gemm_bt_kernel<false><<<dim3(DIM / 128, TOK / 128), 256, 0, stream>>>(
        attn, Wot, (void*)out, TOK, DIM, INNER);
}

// Round 5
// 388.369 us; speedup vs baseline: 1.0110x; 1.0110x over previous
//
#include <hip/hip_runtime.h>
#include <hip/hip_bf16.h>
#include <math.h>

// Problem constants
#define BB    2
#define NN    1024
#define PAST  1024
#define KVL   2048            // PAST + NN
#define DIM   2048
#define HEADS 16
#define DH    128
#define INNER 2048            // HEADS*DH
#define NQKV  6144            // 3*INNER
#define TOK   2048            // BB*NN
#define LN_EPS 1e-5f

typedef __attribute__((ext_vector_type(8)))  short    short8;   // 8 bf16
typedef __attribute__((ext_vector_type(4)))  float    f32x4;
typedef __attribute__((ext_vector_type(16))) float    f32x16;
typedef __attribute__((ext_vector_type(8)))  unsigned short us8;
typedef __attribute__((ext_vector_type(4)))  unsigned short us4;
typedef unsigned short us;

__device__ __forceinline__ float bfbits2f(us u) {
    return __uint_as_float(((unsigned int)u) << 16);
}
__device__ __forceinline__ us f2bfb(float f) {
    union { __hip_bfloat16 h; us u; } cv;
    cv.h = __float2bfloat16(f);           // RNE
    return cv.u;
}
__device__ __forceinline__ unsigned pkbf(float a, float b) {
    return (unsigned)f2bfb(a) | ((unsigned)f2bfb(b) << 16);
}
__device__ __forceinline__ us8 pack8u(float4 a, float4 b) {
    us8 r;
    r[0] = f2bfb(a.x); r[1] = f2bfb(a.y); r[2] = f2bfb(a.z); r[3] = f2bfb(a.w);
    r[4] = f2bfb(b.x); r[5] = f2bfb(b.y); r[6] = f2bfb(b.z); r[7] = f2bfb(b.w);
    return r;
}

// async global->LDS, 16B per lane. LDS dest must be linear (base + lane*16);
// swizzled layouts are achieved by pre-swizzling the GLOBAL source address.
__device__ __forceinline__ void gload_lds16(const void* gsrc, void* ldst) {
    __builtin_amdgcn_global_load_lds(
        (const __attribute__((address_space(1))) void*)gsrc,
        (__attribute__((address_space(3))) void*)ldst, 16, 0, 0);
}

// ---------------------------------------------------------------------------
// K0: transpose + cast: dst[C][R] (bf16) <- src[R][C] (f32). 64x64 tiles.
// ---------------------------------------------------------------------------
__global__ __launch_bounds__(256) void transp_kernel(
    const float* __restrict__ src, us* __restrict__ dst, int R, int C)
{
    const int c0 = blockIdx.x * 64;
    const int r0 = blockIdx.y * 64;
    const int tid = threadIdx.x;

    __shared__ us T[64][68];

    #pragma unroll
    for (int e = 0; e < 4; e++) {
        int idx = tid + e * 256;
        int jr  = idx >> 4;               // row within tile
        int c4  = (idx & 15) * 4;
        float4 v = *reinterpret_cast<const float4*>(
            src + (size_t)(r0 + jr) * C + c0 + c4);
        us4 w;
        w[0] = f2bfb(v.x); w[1] = f2bfb(v.y); w[2] = f2bfb(v.z); w[3] = f2bfb(v.w);
        *reinterpret_cast<us4*>(&T[jr][c4]) = w;
    }
    __syncthreads();

    #pragma unroll
    for (int e = 0; e < 4; e++) {
        int idx = tid + e * 256;
        int d   = idx >> 4;               // col within tile (dst row)
        int k4  = (idx & 15) * 4;
        us4 w;
        w[0] = T[k4 + 0][d];
        w[1] = T[k4 + 1][d];
        w[2] = T[k4 + 2][d];
        w[3] = T[k4 + 3][d];
        *reinterpret_cast<us4*>(dst + (size_t)(c0 + d) * R + r0 + k4) = w;
    }
}

// ---------------------------------------------------------------------------
// K1: LayerNorm over DIM=2048 -> bf16. One block per token.
// ---------------------------------------------------------------------------
__global__ __launch_bounds__(256) void ln_kernel(
    const float* __restrict__ x, const float* __restrict__ g,
    const float* __restrict__ b, us* __restrict__ xn)
{
    const int t   = blockIdx.x;
    const int tid = threadIdx.x;
    const size_t base = (size_t)t * DIM;

    float4 p0 = reinterpret_cast<const float4*>(x + base)[tid * 2 + 0];
    float4 p1 = reinterpret_cast<const float4*>(x + base)[tid * 2 + 1];
    float v[8] = {p0.x, p0.y, p0.z, p0.w, p1.x, p1.y, p1.z, p1.w};

    float s1 = 0.f, s2 = 0.f;
    #pragma unroll
    for (int i = 0; i < 8; i++) { s1 += v[i]; s2 += v[i] * v[i]; }

    #pragma unroll
    for (int off = 32; off; off >>= 1) {
        s1 += __shfl_xor(s1, off);
        s2 += __shfl_xor(s2, off);
    }
    __shared__ float red1[4], red2[4];
    if ((tid & 63) == 0) { red1[tid >> 6] = s1; red2[tid >> 6] = s2; }
    __syncthreads();
    float S1 = red1[0] + red1[1] + red1[2] + red1[3];
    float S2 = red2[0] + red2[1] + red2[2] + red2[3];
    const float inv = 1.0f / (float)DIM;
    float mu  = S1 * inv;
    float var = S2 * inv - mu * mu;
    float rstd = rsqrtf(var + LN_EPS);

    const int d0 = tid * 8;
    float4 oa, ob;
    oa.x = (v[0] - mu) * rstd * g[d0 + 0] + b[d0 + 0];
    oa.y = (v[1] - mu) * rstd * g[d0 + 1] + b[d0 + 1];
    oa.z = (v[2] - mu) * rstd * g[d0 + 2] + b[d0 + 2];
    oa.w = (v[3] - mu) * rstd * g[d0 + 3] + b[d0 + 3];
    ob.x = (v[4] - mu) * rstd * g[d0 + 4] + b[d0 + 4];
    ob.y = (v[5] - mu) * rstd * g[d0 + 5] + b[d0 + 5];
    ob.z = (v[6] - mu) * rstd * g[d0 + 6] + b[d0 + 6];
    ob.w = (v[7] - mu) * rstd * g[d0 + 7] + b[d0 + 7];

    *reinterpret_cast<us8*>(xn + base + d0) = pack8u(oa, ob);
}

// ---------------------------------------------------------------------------
// K2/K5: MFMA GEMM (B^T layout):  C[M][N] = A[M][K] @ Bt[N][K]^T  (bf16 in)
// 128x128 tile, BK=32, 3-buffer LDS ring + counted vmcnt (stage k+2 in
// flight across the barrier). LDS geometry: 64 rows x 128 B (two m-rows per
// LDS row), XOR-swizzled ^((row&7)<<4) via pre-swizzled gload source.
// ---------------------------------------------------------------------------
template<bool OUT_BF16>
__global__ __launch_bounds__(256) void gemm_bt_kernel(
    const us* __restrict__ A, const us* __restrict__ Bt,
    void* __restrict__ Cout, int M, int N, int K)
{
    __shared__ us As[3][128 * 32];     // 8 KB per buffer
    __shared__ us Bs[3][128 * 32];

    const int tid  = threadIdx.x;
    const int wave = tid >> 6, lane = tid & 63;
    const int quad = lane >> 4, l16 = lane & 15;
    const int wm = wave & 1, wn = wave >> 1;
    const int m0 = blockIdx.y * 128, n0 = blockIdx.x * 128;

    f32x4 acc[4][4];
    #pragma unroll
    for (int i = 0; i < 4; i++)
        #pragma unroll
        for (int j = 0; j < 4; j++)
            #pragma unroll
            for (int r = 0; r < 4; r++) acc[i][j][r] = 0.f;

    auto stage = [&](int k0, int buf) {
        #pragma unroll
        for (int e = 0; e < 2; e++) {
            int phys = (e * 256 + tid) * 16;
            int lr   = phys >> 7;                        // LDS row (128 B)
            int offp = (phys & 127) ^ ((lr & 7) << 4);   // logical offset
            int m    = 2 * lr + (offp >> 6);             // m-row in pair
            int kb   = offp & 63;                        // byte within BK=32
            gload_lds16((const char*)(A + (size_t)(m0 + m) * K + k0) + kb,
                        (char*)&As[buf][0] + phys);
            gload_lds16((const char*)(Bt + (size_t)(n0 + m) * K + k0) + kb,
                        (char*)&Bs[buf][0] + phys);
        }
    };

    const int ns = K >> 5;
    stage(0, 0);
    stage(32, 1);
    __builtin_amdgcn_sched_barrier(0);
    asm volatile("s_waitcnt vmcnt(4)" ::: "memory");
    __builtin_amdgcn_s_barrier();
    __builtin_amdgcn_sched_barrier(0);

    int cur = 0;
    for (int ks = 0; ks < ns; ks++) {
        if (ks + 2 < ns) stage((ks + 2) * 32, (ks + 2) % 3);

        short8 af[4], bf[4];
        #pragma unroll
        for (int mi = 0; mi < 4; mi++) {
            int mrow = wm * 64 + mi * 16 + l16;
            int lr   = mrow >> 1;
            int off  = ((mrow & 1) * 64 + quad * 16) ^ ((lr & 7) << 4);
            af[mi] = *reinterpret_cast<const short8*>(
                (const char*)&As[cur][0] + lr * 128 + off);
        }
        #pragma unroll
        for (int ni = 0; ni < 4; ni++) {
            int nrow = wn * 64 + ni * 16 + l16;
            int lr   = nrow >> 1;
            int off  = ((nrow & 1) * 64 + quad * 16) ^ ((lr & 7) << 4);
            bf[ni] = *reinterpret_cast<const short8*>(
                (const char*)&Bs[cur][0] + lr * 128 + off);
        }

        __builtin_amdgcn_s_setprio(1);
        #pragma unroll
        for (int mi = 0; mi < 4; mi++)
            #pragma unroll
            for (int ni = 0; ni < 4; ni++)
                acc[mi][ni] = __builtin_amdgcn_mfma_f32_16x16x32_bf16(
                    af[mi], bf[ni], acc[mi][ni], 0, 0, 0);
        __builtin_amdgcn_s_setprio(0);

        __builtin_amdgcn_sched_barrier(0);
        if (ks + 2 < ns) asm volatile("s_waitcnt vmcnt(4)" ::: "memory");
        else             asm volatile("s_waitcnt vmcnt(0)" ::: "memory");
        __builtin_amdgcn_s_barrier();
        __builtin_amdgcn_sched_barrier(0);
        cur = (cur == 2) ? 0 : cur + 1;
    }

    // epilogue: C/D layout col=l16, row=quad*4+r
    #pragma unroll
    for (int mi = 0; mi < 4; mi++) {
        #pragma unroll
        for (int r = 0; r < 4; r++) {
            size_t row = (size_t)(m0 + wm * 64 + mi * 16 + quad * 4 + r);
            #pragma unroll
            for (int ni = 0; ni < 4; ni++) {
                size_t col = n0 + wn * 64 + ni * 16 + l16;
                if (OUT_BF16)
                    ((us*)Cout)[row * N + col] = f2bfb(acc[mi][ni][r]);
                else
                    ((float*)Cout)[row * N + col] = acc[mi][ni][r];
            }
        }
    }
}

// ---------------------------------------------------------------------------
// K3: RoPE + KV cache assembly. qkv is bf16; outputs f32 + bf16 K copy.
// ---------------------------------------------------------------------------
__global__ __launch_bounds__(256) void rope_kernel(
    const float* __restrict__ past_k, const float* __restrict__ past_v,
    us* __restrict__ qkv, float* __restrict__ out_k, float* __restrict__ out_v,
    us* __restrict__ Kbf)
{
    const int tid  = threadIdx.x;
    const int pid  = blockIdx.x * 4 + (tid >> 6);
    const int lane = tid & 63;

    const int b   = pid / (HEADS * KVL);
    const int rem = pid - b * (HEADS * KVL);
    const int h   = rem / KVL;
    const int pos = rem - h * KVL;

    const float invf = exp2f((float)lane * (-13.287712379549449f / 64.0f));
    float sn, cs;
    sincosf((float)pos * invf, &sn, &cs);

    const size_t obase = ((size_t)(b * HEADS + h) * KVL + pos) * DH + 2 * lane;

    float k0, k1;
    if (pos < PAST) {
        const size_t pbase = ((size_t)(b * HEADS + h) * PAST + pos) * DH + 2 * lane;
        k0 = past_k[pbase];
        k1 = past_k[pbase + 1];
    } else {
        const int t = b * NN + (pos - PAST);
        const us* qp = qkv + (size_t)t * NQKV + INNER + h * DH + 2 * lane;
        k0 = bfbits2f(qp[0]); k1 = bfbits2f(qp[1]);
    }
    float kr0 = k0 * cs - k1 * sn;
    float kr1 = k1 * cs + k0 * sn;
    out_k[obase]     = kr0;
    out_k[obase + 1] = kr1;
    Kbf[obase]       = f2bfb(kr0);
    Kbf[obase + 1]   = f2bfb(kr1);

    if (pos < PAST) {
        const size_t pbase = ((size_t)(b * HEADS + h) * PAST + pos) * DH + 2 * lane;
        out_v[obase]     = past_v[pbase];
        out_v[obase + 1] = past_v[pbase + 1];
    } else {
        const int t = b * NN + (pos - PAST);
        const us* vp = qkv + (size_t)t * NQKV + 2 * INNER + h * DH + 2 * lane;
        out_v[obase]     = bfbits2f(vp[0]);
        out_v[obase + 1] = bfbits2f(vp[1]);
    }

    if (pos >= PAST) {
        const int t = b * NN + (pos - PAST);
        us* qq = qkv + (size_t)t * NQKV + h * DH + 2 * lane;
        float q0 = bfbits2f(qq[0]), q1 = bfbits2f(qq[1]);
        qq[0] = f2bfb(q0 * cs - q1 * sn);
        qq[1] = f2bfb(q1 * cs + q0 * sn);
    }
}

// ---------------------------------------------------------------------------
// K3b: V transpose to bf16: Vtg[bh][d][kv] <- bf16(out_v[bh][kv][d])
// ---------------------------------------------------------------------------
__global__ __launch_bounds__(256) void vtrans_kernel(
    const float* __restrict__ Vc, us* __restrict__ Vtg)
{
    const int jb = blockIdx.x;
    const int db = blockIdx.y;
    const int bh = blockIdx.z;
    const int tid = threadIdx.x;

    __shared__ us T[64][68];

    const float* src = Vc + ((size_t)bh * KVL + jb * 64) * DH + db * 64;
    #pragma unroll
    for (int e = 0; e < 4; e++) {
        int idx = tid + e * 256;
        int jr  = idx >> 4;
        int c4  = (idx & 15) * 4;
        float4 v = *reinterpret_cast<const float4*>(src + (size_t)jr * DH + c4);
        us4 w;
        w[0] = f2bfb(v.x); w[1] = f2bfb(v.y); w[2] = f2bfb(v.z); w[3] = f2bfb(v.w);
        *reinterpret_cast<us4*>(&T[jr][c4]) = w;
    }
    __syncthreads();

    us* dst = Vtg + ((size_t)bh * DH + db * 64) * KVL + jb * 64;
    #pragma unroll
    for (int e = 0; e < 4; e++) {
        int idx = tid + e * 256;
        int d   = idx >> 4;
        int k4  = (idx & 15) * 4;
        us4 w;
        w[0] = T[k4 + 0][d];
        w[1] = T[k4 + 1][d];
        w[2] = T[k4 + 2][d];
        w[3] = T[k4 + 3][d];
        *reinterpret_cast<us4*>(dst + (size_t)d * KVL + k4) = w;
    }
}

// ---------------------------------------------------------------------------
// K4: MFMA flash attention — 32x32x16 MFMA, 32 q-rows/wave, 4 waves/block,
// DOUBLE-buffered LDS (64 KB total -> 2 blocks/CU, 8 waves/CU).
// Swapped QK^T: S col=q=lane&31, row=kv=(reg&3)+8*(reg>>2)+4*(lane>>5).
// PV A-fragment built in-register via cvt_pk + v_permlane32_swap_b32.
// LDS rows are 256 B with full ^((row&15)<<4) swizzle (16 slots): lanes l
// and l+16 alias only -> 2-way (free). V packed 64 rows x 256 B (d, d+64
// share a row). Paired q-tiles {p, 15-p}; XCD-local (b,h) grouping.
// ---------------------------------------------------------------------------
__global__ __launch_bounds__(256) void attn_mfma_kernel(
    const us* __restrict__ qkv,               // [TOK][NQKV] bf16, q roped
    const us* __restrict__ Kbf,               // [bh][KVL][DH] bf16 (roped)
    const us* __restrict__ Vtg,               // [bh][DH][KVL] bf16
    us* __restrict__ Ao)                      // [TOK][INNER] bf16
{
    const int tid  = threadIdx.x;
    const int wave = tid >> 6;
    const int lane = tid & 63;
    const int l32  = lane & 31;
    const int g    = lane >> 5;

    // XCD-aware decode: blk%8 -> XCD; each XCD owns 4 (b,h) groups.
    const int flat = blockIdx.x;
    const int s    = flat >> 3;                 // 0..31
    const int grp  = (flat & 7) + 8 * (s & 3);  // group = h + 16*b
    const int p    = s >> 2;                    // pair 0..7
    const int h    = grp & 15;
    const int b    = grp >> 4;
    const int qtile = (wave < 2) ? p : (15 - p);
    const int qsub  = (wave & 1) * 32;
    const int mynch = 17 + qtile;
    const int nch   = 32 - p;

    __shared__ us Ks[2][64 * 128];   // 16 KB x2: 64 rows x 256 B, swizzled
    __shared__ us Vt[2][64 * 128];   // 16 KB x2: 64 rows x 256 B (d,d+64)

    // Q B-fragments: col=q=lane&31, k = ks*16 + 8*(lane>>5) + e
    short8 qf[8];
    {
        const int qrow = qtile * 64 + qsub + l32;
        const us* qp = qkv + (size_t)(b * NN + qrow) * NQKV + h * DH;
        #pragma unroll
        for (int ks = 0; ks < 8; ks++)
            qf[ks] = *reinterpret_cast<const short8*>(qp + ks * 16 + g * 8);
    }

    f32x16 Oacc[4];
    #pragma unroll
    for (int dt = 0; dt < 4; dt++)
        #pragma unroll
        for (int r = 0; r < 16; r++) Oacc[dt][r] = 0.f;
    float m_run  = -INFINITY;       // running max for q-col (unscaled)
    float l_part = 0.f;             // partial denom over this half's kv

    const us* kptr = Kbf + (size_t)(b * HEADS + h) * KVL * DH;
    const us* vtb  = Vtg + (size_t)(b * HEADS + h) * DH * KVL;
    const float scale = 0.08838834764831845f;
    const float THRU  = 90.50966799f;          // 8 / scale
    const int qgmin = PAST + qtile * 64 + qsub;
    const int qg    = qgmin + l32;

    auto stage = [&](int j0, int buf) {
        // K chunk: 64 rows x 256 B, ^((row&15)<<4) via pre-swizzled src
        #pragma unroll
        for (int e = 0; e < 4; e++) {
            int phys = (e * 256 + tid) * 16;
            int row  = phys >> 8;
            int col  = (phys & 255) ^ ((row & 15) << 4);
            gload_lds16((const char*)(kptr + (size_t)(j0 + row) * DH) + col,
                        (char*)&Ks[buf][0] + phys);
        }
        // V chunk: 64 rows x 256 B; logical off = (d>>6)*128 + kvbyte
        #pragma unroll
        for (int e = 0; e < 4; e++) {
            int phys = (e * 256 + tid) * 16;
            int row  = phys >> 8;
            int offp = (phys & 255) ^ ((row & 15) << 4);
            int d    = row + 64 * (offp >> 7);
            int cb   = offp & 127;
            gload_lds16((const char*)(vtb + (size_t)d * KVL) + j0 * 2 + cb,
                        (char*)&Vt[buf][0] + phys);
        }
    };

    stage(0, 0);
    asm volatile("s_waitcnt vmcnt(0)" ::: "memory");
    __builtin_amdgcn_s_barrier();
    __builtin_amdgcn_sched_barrier(0);

    int cur = 0;
    for (int c = 0; c < nch; c++) {
        const int j0 = c * 64;
        if (c + 1 < nch) stage(j0 + 64, cur ^ 1);   // async prefetch

        if (c < mynch) {
            // ---- QK^T: S[t] = K_tile(t) x Q ----
            f32x16 S[2];
            #pragma unroll
            for (int t = 0; t < 2; t++)
                #pragma unroll
                for (int r = 0; r < 16; r++) S[t][r] = 0.f;

            __builtin_amdgcn_s_setprio(1);
            #pragma unroll
            for (int ks = 0; ks < 8; ks++) {
                #pragma unroll
                for (int t = 0; t < 2; t++) {
                    int row  = t * 32 + l32;
                    int colb = ks * 32 + g * 16;
                    const char* kp = (const char*)&Ks[cur][0] +
                                     row * 256 + (colb ^ ((row & 15) << 4));
                    short8 kb = *reinterpret_cast<const short8*>(kp);
                    S[t] = __builtin_amdgcn_mfma_f32_32x32x16_bf16(
                        kb, qf[ks], S[t], 0, 0, 0);
                }
            }
            __builtin_amdgcn_s_setprio(0);

            // ---- mask (skip when chunk fully valid) + in-lane col max ----
            if (j0 + 63 > qgmin) {
                const int rel = qg - j0;
                #pragma unroll
                for (int t = 0; t < 2; t++)
                    #pragma unroll
                    for (int r = 0; r < 16; r++) {
                        int kvo = t * 32 + (r & 3) + 8 * (r >> 2) + 4 * g;
                        S[t][r] = (kvo <= rel) ? S[t][r] : -INFINITY;
                    }
            }
            float mx = -INFINITY;
            #pragma unroll
            for (int t = 0; t < 2; t++)
                #pragma unroll
                for (int r = 0; r < 16; r++) mx = fmaxf(mx, S[t][r]);
            mx = fmaxf(mx, __shfl_xor(mx, 32));

            // ---- defer-max rescale (rare) ----
            float alpha = 1.f;
            if (__any(mx > m_run + THRU)) {
                float nm = fmaxf(m_run, mx);
                alpha = __expf((m_run - nm) * scale);
                m_run = nm;
                #pragma unroll
                for (int r = 0; r < 16; r++) {
                    float ar = __shfl(alpha, (r & 3) + 8 * (r >> 2) + 4 * g);
                    Oacc[0][r] *= ar; Oacc[1][r] *= ar;
                    Oacc[2][r] *= ar; Oacc[3][r] *= ar;
                }
            }

            // ---- P = exp(S*scale - m*scale), partial sum ----
            const float nmk = -m_run * scale;
            float rs = 0.f;
            #pragma unroll
            for (int t = 0; t < 2; t++)
                #pragma unroll
                for (int r = 0; r < 16; r++) {
                    float pv = __expf(fmaf(S[t][r], scale, nmk));
                    S[t][r] = pv;
                    rs += pv;
                }
            l_part = l_part * alpha + rs;

            // ---- build PV A-fragments in-register (cvt_pk + permlane) ----
            // frag(ks=2t+u) elem e=4a+i <- group-a lane's S[t][i + 4*(2u+g)]
            short8 paf[4];
            #pragma unroll
            for (int t = 0; t < 2; t++)
                #pragma unroll
                for (int u = 0; u < 2; u++) {
                    unsigned cA = pkbf(S[t][8*u + 0], S[t][8*u + 1]);
                    unsigned cB = pkbf(S[t][8*u + 2], S[t][8*u + 3]);
                    unsigned dA = pkbf(S[t][8*u + 4], S[t][8*u + 5]);
                    unsigned dB = pkbf(S[t][8*u + 6], S[t][8*u + 7]);
                    asm volatile("v_permlane32_swap_b32 %0, %1"
                                 : "+v"(cA), "+v"(dA));
                    asm volatile("v_permlane32_swap_b32 %0, %1"
                                 : "+v"(cB), "+v"(dB));
                    union { unsigned u4[4]; short8 s8; } fb;
                    fb.u4[0] = cA; fb.u4[1] = cB; fb.u4[2] = dA; fb.u4[3] = dB;
                    paf[t * 2 + u] = fb.s8;
                }

            // ---- PV ----
            __builtin_amdgcn_s_setprio(1);
            #pragma unroll
            for (int ks = 0; ks < 4; ks++) {
                #pragma unroll
                for (int dt = 0; dt < 4; dt++) {
                    int d    = dt * 32 + l32;
                    int lr   = d & 63;
                    int off  = (((d >> 6) << 7) + ks * 32 + g * 16)
                               ^ ((lr & 15) << 4);
                    const char* vp = (const char*)&Vt[cur][0] +
                                     lr * 256 + off;
                    short8 vb = *reinterpret_cast<const short8*>(vp);
                    Oacc[dt] = __builtin_amdgcn_mfma_f32_32x32x16_bf16(
                        paf[ks], vb, Oacc[dt], 0, 0, 0);
                }
            }
            __builtin_amdgcn_s_setprio(0);
        }

        __builtin_amdgcn_sched_barrier(0);
        asm volatile("s_waitcnt vmcnt(0)" ::: "memory");
        __builtin_amdgcn_s_barrier();
        __builtin_amdgcn_sched_barrier(0);
        cur ^= 1;
    }

    // final denom: combine g-halves (cols identical), per-row redistribute
    l_part += __shfl_xor(l_part, 32);
    float linv = 1.f / l_part;
    #pragma unroll
    for (int r = 0; r < 16; r++) {
        int qr = (r & 3) + 8 * (r >> 2) + 4 * g;
        float iv = __shfl(linv, qr);
        int qrow = qtile * 64 + qsub + qr;
        us* dst = Ao + (size_t)(b * NN + qrow) * INNER + h * DH + l32;
        #pragma unroll
        for (int dt = 0; dt < 4; dt++)
            dst[dt * 32] = f2bfb(Oacc[dt][r] * iv);
    }
}

// ---------------------------------------------------------------------------
extern "C" void kernel_launch(void* const* d_in, const int* in_sizes, int n_in,
                              void* d_out, int out_size, void* d_ws, size_t ws_size,
                              hipStream_t stream)
{
    const float* x      = (const float*)d_in[0];
    const float* past_k = (const float*)d_in[1];
    const float* past_v = (const float*)d_in[2];
    // d_in[3] = mask (unused; computed analytically)
    const float* w_qkv  = (const float*)d_in[4];
    const float* w_out  = (const float*)d_in[5];
    const float* ln_g   = (const float*)d_in[6];
    const float* ln_b   = (const float*)d_in[7];

    float* out   = (float*)d_out;                      // [B,N,DIM]
    float* out_k = out   + (size_t)BB * NN * DIM;      // [B,H,KVL,DH]
    float* out_v = out_k + (size_t)BB * HEADS * KVL * DH;

    // ws (bf16 buffers), 80 MB total:
    us* xn   = (us*)d_ws;                              // [TOK][DIM]     8 MB
    us* qkv  = xn  + (size_t)TOK * DIM;                // [TOK][NQKV]   24 MB
    us* Wqt  = qkv + (size_t)TOK * NQKV;               // [NQKV][DIM]   24 MB
    us* Wot  = Wqt + (size_t)NQKV * DIM;               // [DIM][INNER]   8 MB
    us* Vtg  = Wot + (size_t)DIM * INNER;              // [bh][DH][KVL] 16 MB
    us* attn = xn;   // alias: xn dead after qkv GEMM  // [TOK][INNER]   8 MB
    us* Kbf  = Wqt;  // alias: Wqt dead after qkv GEMM // [bh][KVL][DH] 16.7 MB

    transp_kernel<<<dim3(NQKV / 64, DIM / 64), 256, 0, stream>>>(
        w_qkv, Wqt, DIM, NQKV);
    transp_kernel<<<dim3(DIM / 64, INNER / 64), 256, 0, stream>>>(
        w_out, Wot, INNER, DIM);

    ln_kernel<<<TOK, 256, 0, stream>>>(x, ln_g, ln_b, xn);

    gemm_bt_kernel<true><<<dim3(NQKV / 128, TOK / 128), 256, 0, stream>>>(
        xn, Wqt, (void*)qkv, TOK, NQKV, DIM);

    rope_kernel<<<(BB * HEADS * KVL) / 4, 256, 0, stream>>>(
        past_k, past_v, qkv, out_k, out_v, Kbf);

    vtrans_kernel<<<dim3(KVL / 64, DH / 64, BB * HEADS), 256, 0, stream>>>(
        out_v, Vtg);

    attn_mfma_kernel<<<256, 256, 0, stream>>>(
        qkv, Kbf, Vtg, attn);

    gemm_bt_kernel<false><<<dim3(DIM / 128, TOK / 128), 256, 0, stream>>>(
        attn, Wot, (void*)out, TOK, DIM, INNER);
}

// Round 6
// 362.943 us; speedup vs baseline: 1.0818x; 1.0701x over previous
//
#include <hip/hip_runtime.h>
#include <hip/hip_bf16.h>
#include <math.h>

// Problem constants
#define BB    2
#define NN    1024
#define PAST  1024
#define KVL   2048            // PAST + NN
#define DIM   2048
#define HEADS 16
#define DH    128
#define INNER 2048            // HEADS*DH
#define NQKV  6144            // 3*INNER
#define TOK   2048            // BB*NN
#define LN_EPS 1e-5f

typedef __attribute__((ext_vector_type(8)))  short    short8;   // 8 bf16
typedef __attribute__((ext_vector_type(4)))  float    f32x4;
typedef __attribute__((ext_vector_type(16))) float    f32x16;
typedef __attribute__((ext_vector_type(8)))  unsigned short us8;
typedef __attribute__((ext_vector_type(4)))  unsigned short us4;
typedef unsigned short us;

__device__ __forceinline__ float bfbits2f(us u) {
    return __uint_as_float(((unsigned int)u) << 16);
}
__device__ __forceinline__ us f2bfb(float f) {
    union { __hip_bfloat16 h; us u; } cv;
    cv.h = __float2bfloat16(f);           // RNE
    return cv.u;
}
__device__ __forceinline__ unsigned pkbf(float a, float b) {
    return (unsigned)f2bfb(a) | ((unsigned)f2bfb(b) << 16);
}
__device__ __forceinline__ us8 pack8u(float4 a, float4 b) {
    us8 r;
    r[0] = f2bfb(a.x); r[1] = f2bfb(a.y); r[2] = f2bfb(a.z); r[3] = f2bfb(a.w);
    r[4] = f2bfb(b.x); r[5] = f2bfb(b.y); r[6] = f2bfb(b.z); r[7] = f2bfb(b.w);
    return r;
}

// async global->LDS, 16B per lane. LDS dest must be linear (base + lane*16);
// swizzled layouts are achieved by pre-swizzling the GLOBAL source address.
__device__ __forceinline__ void gload_lds16(const void* gsrc, void* ldst) {
    __builtin_amdgcn_global_load_lds(
        (const __attribute__((address_space(1))) void*)gsrc,
        (__attribute__((address_space(3))) void*)ldst, 16, 0, 0);
}

// ---------------------------------------------------------------------------
// K0: transpose + cast: dst[C][R] (bf16) <- src[R][C] (f32). 64x64 tiles.
// ---------------------------------------------------------------------------
__global__ __launch_bounds__(256) void transp_kernel(
    const float* __restrict__ src, us* __restrict__ dst, int R, int C)
{
    const int c0 = blockIdx.x * 64;
    const int r0 = blockIdx.y * 64;
    const int tid = threadIdx.x;

    __shared__ us T[64][68];

    #pragma unroll
    for (int e = 0; e < 4; e++) {
        int idx = tid + e * 256;
        int jr  = idx >> 4;               // row within tile
        int c4  = (idx & 15) * 4;
        float4 v = *reinterpret_cast<const float4*>(
            src + (size_t)(r0 + jr) * C + c0 + c4);
        us4 w;
        w[0] = f2bfb(v.x); w[1] = f2bfb(v.y); w[2] = f2bfb(v.z); w[3] = f2bfb(v.w);
        *reinterpret_cast<us4*>(&T[jr][c4]) = w;
    }
    __syncthreads();

    #pragma unroll
    for (int e = 0; e < 4; e++) {
        int idx = tid + e * 256;
        int d   = idx >> 4;               // col within tile (dst row)
        int k4  = (idx & 15) * 4;
        us4 w;
        w[0] = T[k4 + 0][d];
        w[1] = T[k4 + 1][d];
        w[2] = T[k4 + 2][d];
        w[3] = T[k4 + 3][d];
        *reinterpret_cast<us4*>(dst + (size_t)(c0 + d) * R + r0 + k4) = w;
    }
}

// ---------------------------------------------------------------------------
// K1: LayerNorm over DIM=2048 -> bf16. One block per token.
// ---------------------------------------------------------------------------
__global__ __launch_bounds__(256) void ln_kernel(
    const float* __restrict__ x, const float* __restrict__ g,
    const float* __restrict__ b, us* __restrict__ xn)
{
    const int t   = blockIdx.x;
    const int tid = threadIdx.x;
    const size_t base = (size_t)t * DIM;

    float4 p0 = reinterpret_cast<const float4*>(x + base)[tid * 2 + 0];
    float4 p1 = reinterpret_cast<const float4*>(x + base)[tid * 2 + 1];
    float v[8] = {p0.x, p0.y, p0.z, p0.w, p1.x, p1.y, p1.z, p1.w};

    float s1 = 0.f, s2 = 0.f;
    #pragma unroll
    for (int i = 0; i < 8; i++) { s1 += v[i]; s2 += v[i] * v[i]; }

    #pragma unroll
    for (int off = 32; off; off >>= 1) {
        s1 += __shfl_xor(s1, off);
        s2 += __shfl_xor(s2, off);
    }
    __shared__ float red1[4], red2[4];
    if ((tid & 63) == 0) { red1[tid >> 6] = s1; red2[tid >> 6] = s2; }
    __syncthreads();
    float S1 = red1[0] + red1[1] + red1[2] + red1[3];
    float S2 = red2[0] + red2[1] + red2[2] + red2[3];
    const float inv = 1.0f / (float)DIM;
    float mu  = S1 * inv;
    float var = S2 * inv - mu * mu;
    float rstd = rsqrtf(var + LN_EPS);

    const int d0 = tid * 8;
    float4 oa, ob;
    oa.x = (v[0] - mu) * rstd * g[d0 + 0] + b[d0 + 0];
    oa.y = (v[1] - mu) * rstd * g[d0 + 1] + b[d0 + 1];
    oa.z = (v[2] - mu) * rstd * g[d0 + 2] + b[d0 + 2];
    oa.w = (v[3] - mu) * rstd * g[d0 + 3] + b[d0 + 3];
    ob.x = (v[4] - mu) * rstd * g[d0 + 4] + b[d0 + 4];
    ob.y = (v[5] - mu) * rstd * g[d0 + 5] + b[d0 + 5];
    ob.z = (v[6] - mu) * rstd * g[d0 + 6] + b[d0 + 6];
    ob.w = (v[7] - mu) * rstd * g[d0 + 7] + b[d0 + 7];

    *reinterpret_cast<us8*>(xn + base + d0) = pack8u(oa, ob);
}

// ---------------------------------------------------------------------------
// K2/K5: MFMA GEMM (B^T layout):  C[M][N] = A[M][K] @ Bt[N][K]^T  (bf16 in)
// 128x128 tile, BK=32, 3-buffer LDS ring + counted vmcnt (stage k+2 in
// flight across the barrier). LDS geometry: 64 rows x 128 B (two m-rows per
// LDS row), XOR-swizzled ^((row&7)<<4) via pre-swizzled gload source.
// ---------------------------------------------------------------------------
template<bool OUT_BF16>
__global__ __launch_bounds__(256) void gemm_bt_kernel(
    const us* __restrict__ A, const us* __restrict__ Bt,
    void* __restrict__ Cout, int M, int N, int K)
{
    __shared__ us As[3][128 * 32];     // 8 KB per buffer
    __shared__ us Bs[3][128 * 32];

    const int tid  = threadIdx.x;
    const int wave = tid >> 6, lane = tid & 63;
    const int quad = lane >> 4, l16 = lane & 15;
    const int wm = wave & 1, wn = wave >> 1;
    const int m0 = blockIdx.y * 128, n0 = blockIdx.x * 128;

    f32x4 acc[4][4];
    #pragma unroll
    for (int i = 0; i < 4; i++)
        #pragma unroll
        for (int j = 0; j < 4; j++)
            #pragma unroll
            for (int r = 0; r < 4; r++) acc[i][j][r] = 0.f;

    auto stage = [&](int k0, int buf) {
        #pragma unroll
        for (int e = 0; e < 2; e++) {
            int phys = (e * 256 + tid) * 16;
            int lr   = phys >> 7;                        // LDS row (128 B)
            int offp = (phys & 127) ^ ((lr & 7) << 4);   // logical offset
            int m    = 2 * lr + (offp >> 6);             // m-row in pair
            int kb   = offp & 63;                        // byte within BK=32
            gload_lds16((const char*)(A + (size_t)(m0 + m) * K + k0) + kb,
                        (char*)&As[buf][0] + phys);
            gload_lds16((const char*)(Bt + (size_t)(n0 + m) * K + k0) + kb,
                        (char*)&Bs[buf][0] + phys);
        }
    };

    const int ns = K >> 5;
    stage(0, 0);
    stage(32, 1);
    __builtin_amdgcn_sched_barrier(0);
    asm volatile("s_waitcnt vmcnt(4)" ::: "memory");
    __builtin_amdgcn_s_barrier();
    __builtin_amdgcn_sched_barrier(0);

    int cur = 0;
    for (int ks = 0; ks < ns; ks++) {
        if (ks + 2 < ns) stage((ks + 2) * 32, (ks + 2) % 3);

        short8 af[4], bf[4];
        #pragma unroll
        for (int mi = 0; mi < 4; mi++) {
            int mrow = wm * 64 + mi * 16 + l16;
            int lr   = mrow >> 1;
            int off  = ((mrow & 1) * 64 + quad * 16) ^ ((lr & 7) << 4);
            af[mi] = *reinterpret_cast<const short8*>(
                (const char*)&As[cur][0] + lr * 128 + off);
        }
        #pragma unroll
        for (int ni = 0; ni < 4; ni++) {
            int nrow = wn * 64 + ni * 16 + l16;
            int lr   = nrow >> 1;
            int off  = ((nrow & 1) * 64 + quad * 16) ^ ((lr & 7) << 4);
            bf[ni] = *reinterpret_cast<const short8*>(
                (const char*)&Bs[cur][0] + lr * 128 + off);
        }

        __builtin_amdgcn_s_setprio(1);
        #pragma unroll
        for (int mi = 0; mi < 4; mi++)
            #pragma unroll
            for (int ni = 0; ni < 4; ni++)
                acc[mi][ni] = __builtin_amdgcn_mfma_f32_16x16x32_bf16(
                    af[mi], bf[ni], acc[mi][ni], 0, 0, 0);
        __builtin_amdgcn_s_setprio(0);

        __builtin_amdgcn_sched_barrier(0);
        if (ks + 2 < ns) asm volatile("s_waitcnt vmcnt(4)" ::: "memory");
        else             asm volatile("s_waitcnt vmcnt(0)" ::: "memory");
        __builtin_amdgcn_s_barrier();
        __builtin_amdgcn_sched_barrier(0);
        cur = (cur == 2) ? 0 : cur + 1;
    }

    // epilogue: C/D layout col=l16, row=quad*4+r
    #pragma unroll
    for (int mi = 0; mi < 4; mi++) {
        #pragma unroll
        for (int r = 0; r < 4; r++) {
            size_t row = (size_t)(m0 + wm * 64 + mi * 16 + quad * 4 + r);
            #pragma unroll
            for (int ni = 0; ni < 4; ni++) {
                size_t col = n0 + wn * 64 + ni * 16 + l16;
                if (OUT_BF16)
                    ((us*)Cout)[row * N + col] = f2bfb(acc[mi][ni][r]);
                else
                    ((float*)Cout)[row * N + col] = acc[mi][ni][r];
            }
        }
    }
}

// ---------------------------------------------------------------------------
// K3: RoPE + KV cache assembly. qkv is bf16; outputs f32 + bf16 K copy.
// ---------------------------------------------------------------------------
__global__ __launch_bounds__(256) void rope_kernel(
    const float* __restrict__ past_k, const float* __restrict__ past_v,
    us* __restrict__ qkv, float* __restrict__ out_k, float* __restrict__ out_v,
    us* __restrict__ Kbf)
{
    const int tid  = threadIdx.x;
    const int pid  = blockIdx.x * 4 + (tid >> 6);
    const int lane = tid & 63;

    const int b   = pid / (HEADS * KVL);
    const int rem = pid - b * (HEADS * KVL);
    const int h   = rem / KVL;
    const int pos = rem - h * KVL;

    const float invf = exp2f((float)lane * (-13.287712379549449f / 64.0f));
    float sn, cs;
    sincosf((float)pos * invf, &sn, &cs);

    const size_t obase = ((size_t)(b * HEADS + h) * KVL + pos) * DH + 2 * lane;

    float k0, k1;
    if (pos < PAST) {
        const size_t pbase = ((size_t)(b * HEADS + h) * PAST + pos) * DH + 2 * lane;
        k0 = past_k[pbase];
        k1 = past_k[pbase + 1];
    } else {
        const int t = b * NN + (pos - PAST);
        const us* qp = qkv + (size_t)t * NQKV + INNER + h * DH + 2 * lane;
        k0 = bfbits2f(qp[0]); k1 = bfbits2f(qp[1]);
    }
    float kr0 = k0 * cs - k1 * sn;
    float kr1 = k1 * cs + k0 * sn;
    out_k[obase]     = kr0;
    out_k[obase + 1] = kr1;
    Kbf[obase]       = f2bfb(kr0);
    Kbf[obase + 1]   = f2bfb(kr1);

    if (pos < PAST) {
        const size_t pbase = ((size_t)(b * HEADS + h) * PAST + pos) * DH + 2 * lane;
        out_v[obase]     = past_v[pbase];
        out_v[obase + 1] = past_v[pbase + 1];
    } else {
        const int t = b * NN + (pos - PAST);
        const us* vp = qkv + (size_t)t * NQKV + 2 * INNER + h * DH + 2 * lane;
        out_v[obase]     = bfbits2f(vp[0]);
        out_v[obase + 1] = bfbits2f(vp[1]);
    }

    if (pos >= PAST) {
        const int t = b * NN + (pos - PAST);
        us* qq = qkv + (size_t)t * NQKV + h * DH + 2 * lane;
        float q0 = bfbits2f(qq[0]), q1 = bfbits2f(qq[1]);
        qq[0] = f2bfb(q0 * cs - q1 * sn);
        qq[1] = f2bfb(q1 * cs + q0 * sn);
    }
}

// ---------------------------------------------------------------------------
// K3b: V transpose to bf16: Vtg[bh][d][kv] <- bf16(out_v[bh][kv][d])
// ---------------------------------------------------------------------------
__global__ __launch_bounds__(256) void vtrans_kernel(
    const float* __restrict__ Vc, us* __restrict__ Vtg)
{
    const int jb = blockIdx.x;
    const int db = blockIdx.y;
    const int bh = blockIdx.z;
    const int tid = threadIdx.x;

    __shared__ us T[64][68];

    const float* src = Vc + ((size_t)bh * KVL + jb * 64) * DH + db * 64;
    #pragma unroll
    for (int e = 0; e < 4; e++) {
        int idx = tid + e * 256;
        int jr  = idx >> 4;
        int c4  = (idx & 15) * 4;
        float4 v = *reinterpret_cast<const float4*>(src + (size_t)jr * DH + c4);
        us4 w;
        w[0] = f2bfb(v.x); w[1] = f2bfb(v.y); w[2] = f2bfb(v.z); w[3] = f2bfb(v.w);
        *reinterpret_cast<us4*>(&T[jr][c4]) = w;
    }
    __syncthreads();

    us* dst = Vtg + ((size_t)bh * DH + db * 64) * KVL + jb * 64;
    #pragma unroll
    for (int e = 0; e < 4; e++) {
        int idx = tid + e * 256;
        int d   = idx >> 4;
        int k4  = (idx & 15) * 4;
        us4 w;
        w[0] = T[k4 + 0][d];
        w[1] = T[k4 + 1][d];
        w[2] = T[k4 + 2][d];
        w[3] = T[k4 + 3][d];
        *reinterpret_cast<us4*>(dst + (size_t)d * KVL + k4) = w;
    }
}

// ---------------------------------------------------------------------------
// K4: MFMA flash attention — 32x32x16, 32 q-rows/wave, 8 waves/block (512thr)
// with KV-PARITY SPLIT: waves 0-3 process even chunks, waves 4-7 odd chunks,
// for the same q-rows (tiles p and 15-p). Doubles wave-parallelism to
// 2 waves/SIMD (the grid otherwise caps at 1/SIMD: 1024 q-waves total).
// Partial online-softmax states merged exactly at the end via LDS scratch:
// O = (O0*f0 + O1*f1) / (l0*f0 + l1*f1), f_i = exp((m_i - M)*scale).
// LDS: 2 ring buffers x 2 parity chunks x (16K K + 16K V) = 128 KB.
// Zero-conflict full-width swizzle ^((row&15)<<4); in-register P via
// cvt_pk + v_permlane32_swap_b32; defer-max; XCD-local (b,h) grouping.
// ---------------------------------------------------------------------------
__global__ __launch_bounds__(512) void attn_mfma_kernel(
    const us* __restrict__ qkv,               // [TOK][NQKV] bf16, q roped
    const us* __restrict__ Kbf,               // [bh][KVL][DH] bf16 (roped)
    const us* __restrict__ Vtg,               // [bh][DH][KVL] bf16
    us* __restrict__ Ao)                      // [TOK][INNER] bf16
{
    const int tid  = threadIdx.x;
    const int wave = tid >> 6;
    const int lane = tid & 63;
    const int l32  = lane & 31;
    const int g    = lane >> 5;
    const int wv   = wave & 3;      // q-role within parity group
    const int mypar= wave >> 2;     // kv parity (0=even chunks, 1=odd)

    // XCD-aware decode: blk%8 -> XCD; each XCD owns 4 (b,h) groups.
    const int flat = blockIdx.x;
    const int s    = flat >> 3;                 // 0..31
    const int grp  = (flat & 7) + 8 * (s & 3);  // group = h + 16*b
    const int p    = s >> 2;                    // pair 0..7
    const int h    = grp & 15;
    const int b    = grp >> 4;
    const int qtile = (wv < 2) ? p : (15 - p);
    const int qsub  = (wv & 1) * 32;
    const int mynch = 17 + qtile;               // causal chunk count for tile
    const int nch   = 32 - p;                   // max over the two tiles
    const int nit   = (nch + 1) >> 1;           // parity iterations

    __shared__ us Ks[2][2 * 64 * 128];   // [buf][par*8192 us]: 32 KB/buf
    __shared__ us Vt[2][2 * 64 * 128];   // same

    // Q B-fragments: col=q=lane&31, k = ks*16 + 8*g + e
    short8 qf[8];
    {
        const int qrow = qtile * 64 + qsub + l32;
        const us* qp = qkv + (size_t)(b * NN + qrow) * NQKV + h * DH;
        #pragma unroll
        for (int ks = 0; ks < 8; ks++)
            qf[ks] = *reinterpret_cast<const short8*>(qp + ks * 16 + g * 8);
    }

    f32x16 Oacc[4];
    #pragma unroll
    for (int dt = 0; dt < 4; dt++)
        #pragma unroll
        for (int r = 0; r < 16; r++) Oacc[dt][r] = 0.f;
    float m_run  = -INFINITY;       // running (deferred) max, q = l32
    float l_part = 0.f;             // partial denom over this g-half's kv

    const us* kptr = Kbf + (size_t)(b * HEADS + h) * KVL * DH;
    const us* vtb  = Vtg + (size_t)(b * HEADS + h) * DH * KVL;
    const float scale = 0.08838834764831845f;
    const float THRU  = 90.50966799f;          // 8 / scale
    const int qgmin = PAST + qtile * 64 + qsub;
    const int qg    = qgmin + l32;

    // stage chunk pair {2*it2, 2*it2+1} into buffer buf (both parities)
    auto stage = [&](int it2, int buf) {
        #pragma unroll
        for (int e = 0; e < 4; e++) {
            int phys = (e * 512 + tid) * 16;         // 0..32 KB
            int par  = phys >> 14;
            int pc   = phys & 16383;
            int row  = pc >> 8;
            int col  = (pc & 255) ^ ((row & 15) << 4);
            int j0   = (2 * it2 + par) * 64;
            gload_lds16((const char*)(kptr + (size_t)(j0 + row) * DH) + col,
                        (char*)&Ks[buf][0] + phys);
        }
        #pragma unroll
        for (int e = 0; e < 4; e++) {
            int phys = (e * 512 + tid) * 16;
            int par  = phys >> 14;
            int pc   = phys & 16383;
            int row  = pc >> 8;
            int offp = (pc & 255) ^ ((row & 15) << 4);
            int d    = row + 64 * (offp >> 7);
            int cb   = offp & 127;
            int j0   = (2 * it2 + par) * 64;
            gload_lds16((const char*)(vtb + (size_t)d * KVL) + j0 * 2 + cb,
                        (char*)&Vt[buf][0] + phys);
        }
    };

    stage(0, 0);
    asm volatile("s_waitcnt vmcnt(0)" ::: "memory");
    __builtin_amdgcn_s_barrier();
    __builtin_amdgcn_sched_barrier(0);

    int cur = 0;
    for (int it = 0; it < nit; it++) {
        if (it + 1 < nit) stage(it + 1, cur ^ 1);   // async prefetch pair

        const int c = 2 * it + mypar;
        if (c < mynch) {
            const int j0 = c * 64;
            const char* kbase = (const char*)&Ks[cur][0] + mypar * 16384;
            const char* vbase = (const char*)&Vt[cur][0] + mypar * 16384;

            // ---- QK^T: S[t] = K_tile(t) x Q ----
            f32x16 S[2];
            #pragma unroll
            for (int t = 0; t < 2; t++)
                #pragma unroll
                for (int r = 0; r < 16; r++) S[t][r] = 0.f;

            __builtin_amdgcn_s_setprio(1);
            #pragma unroll
            for (int ks = 0; ks < 8; ks++) {
                #pragma unroll
                for (int t = 0; t < 2; t++) {
                    int row  = t * 32 + l32;
                    int colb = ks * 32 + g * 16;
                    const char* kp = kbase +
                                     row * 256 + (colb ^ ((row & 15) << 4));
                    short8 kb = *reinterpret_cast<const short8*>(kp);
                    S[t] = __builtin_amdgcn_mfma_f32_32x32x16_bf16(
                        kb, qf[ks], S[t], 0, 0, 0);
                }
            }
            __builtin_amdgcn_s_setprio(0);

            // ---- mask (skip when chunk fully valid) + in-lane col max ----
            if (j0 + 63 > qgmin) {
                const int rel = qg - j0;
                #pragma unroll
                for (int t = 0; t < 2; t++)
                    #pragma unroll
                    for (int r = 0; r < 16; r++) {
                        int kvo = t * 32 + (r & 3) + 8 * (r >> 2) + 4 * g;
                        S[t][r] = (kvo <= rel) ? S[t][r] : -INFINITY;
                    }
            }
            float mx = -INFINITY;
            #pragma unroll
            for (int t = 0; t < 2; t++)
                #pragma unroll
                for (int r = 0; r < 16; r++) mx = fmaxf(mx, S[t][r]);
            mx = fmaxf(mx, __shfl_xor(mx, 32));

            // ---- defer-max rescale (rare) ----
            float alpha = 1.f;
            if (__any(mx > m_run + THRU)) {
                float nm = fmaxf(m_run, mx);
                alpha = __expf((m_run - nm) * scale);
                m_run = nm;
                #pragma unroll
                for (int r = 0; r < 16; r++) {
                    float ar = __shfl(alpha, (r & 3) + 8 * (r >> 2) + 4 * g);
                    Oacc[0][r] *= ar; Oacc[1][r] *= ar;
                    Oacc[2][r] *= ar; Oacc[3][r] *= ar;
                }
            }

            // ---- P = exp(S*scale - m*scale), partial sum ----
            const float nmk = -m_run * scale;
            float rs = 0.f;
            #pragma unroll
            for (int t = 0; t < 2; t++)
                #pragma unroll
                for (int r = 0; r < 16; r++) {
                    float pv = __expf(fmaf(S[t][r], scale, nmk));
                    S[t][r] = pv;
                    rs += pv;
                }
            l_part = l_part * alpha + rs;

            // ---- build PV A-fragments in-register (cvt_pk + permlane) ----
            short8 paf[4];
            #pragma unroll
            for (int t = 0; t < 2; t++)
                #pragma unroll
                for (int u = 0; u < 2; u++) {
                    unsigned cA = pkbf(S[t][8*u + 0], S[t][8*u + 1]);
                    unsigned cB = pkbf(S[t][8*u + 2], S[t][8*u + 3]);
                    unsigned dA = pkbf(S[t][8*u + 4], S[t][8*u + 5]);
                    unsigned dB = pkbf(S[t][8*u + 6], S[t][8*u + 7]);
                    asm volatile("v_permlane32_swap_b32 %0, %1"
                                 : "+v"(cA), "+v"(dA));
                    asm volatile("v_permlane32_swap_b32 %0, %1"
                                 : "+v"(cB), "+v"(dB));
                    union { unsigned u4[4]; short8 s8; } fb;
                    fb.u4[0] = cA; fb.u4[1] = cB; fb.u4[2] = dA; fb.u4[3] = dB;
                    paf[t * 2 + u] = fb.s8;
                }

            // ---- PV ----
            __builtin_amdgcn_s_setprio(1);
            #pragma unroll
            for (int ks = 0; ks < 4; ks++) {
                #pragma unroll
                for (int dt = 0; dt < 4; dt++) {
                    int d    = dt * 32 + l32;
                    int lr   = d & 63;
                    int off  = (((d >> 6) << 7) + ks * 32 + g * 16)
                               ^ ((lr & 15) << 4);
                    const char* vp = vbase + lr * 256 + off;
                    short8 vb = *reinterpret_cast<const short8*>(vp);
                    Oacc[dt] = __builtin_amdgcn_mfma_f32_32x32x16_bf16(
                        paf[ks], vb, Oacc[dt], 0, 0, 0);
                }
            }
            __builtin_amdgcn_s_setprio(0);
        }

        __builtin_amdgcn_sched_barrier(0);
        asm volatile("s_waitcnt vmcnt(0)" ::: "memory");
        __builtin_amdgcn_s_barrier();
        __builtin_amdgcn_sched_barrier(0);
        cur ^= 1;
    }

    // ---- merge parity partials, then write (lower waves only) ----
    l_part += __shfl_xor(l_part, 32);       // combine g-halves (same q cols)

    float* scr = (float*)&Ks[0][0];         // scratch: 66 KB of the 128 KB
    float* Sm  = scr;                       // [4][64]
    float* Sl  = scr + 256;                 // [4][64]
    float* SO  = scr + 512;                 // [4][64 idx][64 lanes]

    if (mypar == 1) {
        Sm[wv * 64 + lane] = m_run;
        Sl[wv * 64 + lane] = l_part;
        float* ob = SO + wv * 4096 + lane;
        #pragma unroll
        for (int dt = 0; dt < 4; dt++)
            #pragma unroll
            for (int r = 0; r < 16; r++)
                ob[(dt * 16 + r) * 64] = Oacc[dt][r];
    }
    __syncthreads();
    if (mypar == 0) {
        float m1 = Sm[wv * 64 + lane];
        float l1 = Sl[wv * 64 + lane];
        float M  = fmaxf(m_run, m1);
        float f0 = __expf((m_run - M) * scale);
        float f1 = __expf((m1 - M) * scale);
        float linv = 1.f / (l_part * f0 + l1 * f1);

        const float* ob = SO + wv * 4096 + lane;
        #pragma unroll
        for (int r = 0; r < 16; r++) {
            int qr = (r & 3) + 8 * (r >> 2) + 4 * g;
            float ivr = __shfl(linv, qr);
            float f0r = __shfl(f0, qr);
            float f1r = __shfl(f1, qr);
            int qrow = qtile * 64 + qsub + qr;
            us* dst = Ao + (size_t)(b * NN + qrow) * INNER + h * DH + l32;
            #pragma unroll
            for (int dt = 0; dt < 4; dt++) {
                float o1 = ob[(dt * 16 + r) * 64];
                dst[dt * 32] = f2bfb((Oacc[dt][r] * f0r + o1 * f1r) * ivr);
            }
        }
    }
}

// ---------------------------------------------------------------------------
extern "C" void kernel_launch(void* const* d_in, const int* in_sizes, int n_in,
                              void* d_out, int out_size, void* d_ws, size_t ws_size,
                              hipStream_t stream)
{
    const float* x      = (const float*)d_in[0];
    const float* past_k = (const float*)d_in[1];
    const float* past_v = (const float*)d_in[2];
    // d_in[3] = mask (unused; computed analytically)
    const float* w_qkv  = (const float*)d_in[4];
    const float* w_out  = (const float*)d_in[5];
    const float* ln_g   = (const float*)d_in[6];
    const float* ln_b   = (const float*)d_in[7];

    float* out   = (float*)d_out;                      // [B,N,DIM]
    float* out_k = out   + (size_t)BB * NN * DIM;      // [B,H,KVL,DH]
    float* out_v = out_k + (size_t)BB * HEADS * KVL * DH;

    // ws (bf16 buffers), 80 MB total:
    us* xn   = (us*)d_ws;                              // [TOK][DIM]     8 MB
    us* qkv  = xn  + (size_t)TOK * DIM;                // [TOK][NQKV]   24 MB
    us* Wqt  = qkv + (size_t)TOK * NQKV;               // [NQKV][DIM]   24 MB
    us* Wot  = Wqt + (size_t)NQKV * DIM;               // [DIM][INNER]   8 MB
    us* Vtg  = Wot + (size_t)DIM * INNER;              // [bh][DH][KVL] 16 MB
    us* attn = xn;   // alias: xn dead after qkv GEMM  // [TOK][INNER]   8 MB
    us* Kbf  = Wqt;  // alias: Wqt dead after qkv GEMM // [bh][KVL][DH] 16.7 MB

    transp_kernel<<<dim3(NQKV / 64, DIM / 64), 256, 0, stream>>>(
        w_qkv, Wqt, DIM, NQKV);
    transp_kernel<<<dim3(DIM / 64, INNER / 64), 256, 0, stream>>>(
        w_out, Wot, INNER, DIM);

    ln_kernel<<<TOK, 256, 0, stream>>>(x, ln_g, ln_b, xn);

    gemm_bt_kernel<true><<<dim3(NQKV / 128, TOK / 128), 256, 0, stream>>>(
        xn, Wqt, (void*)qkv, TOK, NQKV, DIM);

    rope_kernel<<<(BB * HEADS * KVL) / 4, 256, 0, stream>>>(
        past_k, past_v, qkv, out_k, out_v, Kbf);

    vtrans_kernel<<<dim3(KVL / 64, DH / 64, BB * HEADS), 256, 0, stream>>>(
        out_v, Vtg);

    attn_mfma_kernel<<<256, 512, 0, stream>>>(
        qkv, Kbf, Vtg, attn);

    gemm_bt_kernel<false><<<dim3(DIM / 128, TOK / 128), 256, 0, stream>>>(
        attn, Wot, (void*)out, TOK, DIM, INNER);
}